// Round 22
// baseline (271.853 us; speedup 1.0000x reference)
//
#include <hip/hip_runtime.h>

// Round 22 — R20 attn body (faster than R21's) + SPLIT-K over key-tiles:
//  rt<16: one block (<=16 steps). rt>=16: two blocks over disjoint key ranges
//  (<=16 steps each) writing partial (o[64], m, l) per row; merge kernel combines
//  (flash rule), applies masked-row mean(v), and does the no-transpose scatter.
// Critical path 32 -> 16 tile-steps; grid 512 -> 768 blocks.

#define B_ 2
#define T_ 2048
#define E_ 512
#define H_ 8
#define SCALE2 0.044194173824159216f   // 512^-0.5 folded into k

typedef __attribute__((ext_vector_type(8))) short bf16x8;
typedef __attribute__((ext_vector_type(4))) float f32x4;

#define MFMA(a,b,c) __builtin_amdgcn_mfma_f32_16x16x32_bf16((a),(b),(c),0,0,0)

__device__ __forceinline__ unsigned short f2bf(float f){
  unsigned u = __builtin_bit_cast(unsigned, f);
  u += 0x7fffu + ((u >> 16) & 1u);
  return (unsigned short)(u >> 16);
}
__device__ __forceinline__ float bf2f(unsigned short h){
  unsigned u = ((unsigned)h) << 16;
  return __builtin_bit_cast(float, u);
}

// ---------------- QKV projection ----
__global__ __launch_bounds__(256) void prep_qkv(
    const float* __restrict__ x,
    const float* __restrict__ Wq, const float* __restrict__ Wk, const float* __restrict__ Wv,
    unsigned short* __restrict__ qh, unsigned short* __restrict__ ql,
    unsigned short* __restrict__ kb, unsigned short* __restrict__ vb)
{
  int wid = blockIdx.x*4 + (threadIdx.x>>6);
  int o   = threadIdx.x & 63;
  int bh  = wid & 15;
  int rest = wid >> 4;
  int chunk = rest & 255;
  int m = rest >> 8;
  const float* W = (m==0) ? Wq : (m==1) ? Wk : Wv;
  float4 wv[16];
  #pragma unroll
  for (int j=0;j<16;++j) wv[j] = reinterpret_cast<const float4*>(W)[o*16+j];
  if (m==1){
    #pragma unroll
    for (int j=0;j<16;++j){ wv[j].x*=SCALE2; wv[j].y*=SCALE2; wv[j].z*=SCALE2; wv[j].w*=SCALE2; }
  }
  int b = bh>>3, h = bh&7;
  unsigned short* out0 = (m==0) ? qh : (m==1) ? kb : vb;
  for (int tl=0; tl<8; ++tl){
    int t = chunk*8 + tl;
    const float4* xr = reinterpret_cast<const float4*>(x + ((size_t)(b*T_ + t))*E_ + h*64);
    float a0=0.f,a1=0.f,a2=0.f,a3=0.f;
    #pragma unroll
    for (int j=0;j<16;++j){
      float4 xv = xr[j];
      a0 += xv.x*wv[j].x; a1 += xv.y*wv[j].y; a2 += xv.z*wv[j].z; a3 += xv.w*wv[j].w;
    }
    float acc = (a0+a1)+(a2+a3);
    size_t oi = ((size_t)bh*T_ + t)*64 + o;
    if (m==0){
      unsigned short hq = f2bf(acc);
      out0[oi] = hq;
      ql[oi] = f2bf(acc - bf2f(hq));
    } else {
      out0[oi] = f2bf(acc);
    }
  }
}

__global__ void prep_er(const float* __restrict__ Er,
                        unsigned short* __restrict__ eh, unsigned short* __restrict__ el)
{
  int i = (blockIdx.x*blockDim.x + threadIdx.x)*4;
  float4 v = *reinterpret_cast<const float4*>(Er + i);
  unsigned short h0=f2bf(v.x), h1=f2bf(v.y), h2=f2bf(v.z), h3=f2bf(v.w);
  *reinterpret_cast<ushort4*>(&eh[i]) = make_ushort4(h0,h1,h2,h3);
  *reinterpret_cast<ushort4*>(&el[i]) = make_ushort4(
      f2bf(v.x-bf2f(h0)), f2bf(v.y-bf2f(h1)), f2bf(v.z-bf2f(h2)), f2bf(v.w-bf2f(h3)));
}

__global__ void prep_wo(const float* __restrict__ Wo, unsigned short* __restrict__ wob){
  int i = (blockIdx.x*blockDim.x + threadIdx.x)*4;
  float4 v = *reinterpret_cast<const float4*>(Wo + i);
  *reinterpret_cast<ushort4*>(&wob[i]) = make_ushort4(f2bf(v.x),f2bf(v.y),f2bf(v.z),f2bf(v.w));
}

__global__ __launch_bounds__(256) void vsum1(const unsigned short* __restrict__ vb,
                                             float* __restrict__ vpart)
{
  __shared__ float red[4][64];
  int bh = blockIdx.x >> 3, ch = blockIdx.x & 7;
  int s = threadIdx.x & 63, sub = threadIdx.x >> 6;
  const unsigned short* p = vb + ((size_t)bh*T_ + ch*256 + sub*64)*64 + s;
  float acc = 0.f;
  #pragma unroll 8
  for (int t=0;t<64;++t) acc += bf2f(p[(size_t)t*64]);
  red[sub][s] = acc;
  __syncthreads();
  if (sub==0) vpart[(size_t)(bh*8+ch)*64 + s] = red[0][s]+red[1][s]+red[2][s]+red[3][s];
}
__global__ void vsum2(const float* __restrict__ vpart, float* __restrict__ vsum){
  int bh = blockIdx.x, s = threadIdx.x;
  float a = 0.f;
  #pragma unroll
  for (int c=0;c<8;++c) a += vpart[(size_t)(bh*8+c)*64 + s];
  vsum[bh*64+s] = a;
}

// ---------------- split-K flash attention: writes partials (o[64], m, l) ----------
// unit<16: rt=unit, tiles [0, rt+1), half 0. unit>=16: j=unit-16, rt=16+(j>>1),
// half=j&1; nh=ceil((rt+1)/2); half0 tiles [0,nh), half1 [nh, rt+1).
__global__ __launch_bounds__(256,2) void attn(
  const unsigned short* __restrict__ qh, const unsigned short* __restrict__ ql,
  const unsigned short* __restrict__ kb, const unsigned short* __restrict__ vb,
  const unsigned short* __restrict__ eh, const unsigned short* __restrict__ el,
  float* __restrict__ part)
{
  __shared__ float QEs[4][128][20];
  __shared__ unsigned short Ps[4][16][72];
  __shared__ unsigned short Vt[64][72];

  const int tid = threadIdx.x;
  const int w = tid >> 6, lane = tid & 63, g = lane >> 4, q15 = lane & 15;
  const int bid = blockIdx.x;
  const int bh = bid & 15;
  const int unit = bid >> 4;                 // 0..47
  int rt, ts, te, half;
  if (unit < 16){ rt = unit; ts = 0; te = rt+1; half = 0; }
  else {
    int j = unit - 16;
    rt = 16 + (j >> 1);
    half = j & 1;
    int nt = rt + 1;
    int nh = (nt + 1) >> 1;                  // ceil
    if (half == 0){ ts = 0; te = nh; } else { ts = nh; te = nt; }
  }
  const int i0 = rt * 64;
  const int h = bh & 7;

  const size_t qoff = ((size_t)bh*T_ + i0 + 16*w + q15)*64 + 8*g;
  const bf16x8 qa00 = *(const bf16x8*)(qh + qoff);
  const bf16x8 qa01 = *(const bf16x8*)(qh + qoff + 32);
  const bf16x8 qa10 = *(const bf16x8*)(ql + qoff);
  const bf16x8 qa11 = *(const bf16x8*)(ql + qoff + 32);

  f32x4 oacc[4];
  float mrun[4], lrun[4];
  const f32x4 fz = {0.f,0.f,0.f,0.f};
  #pragma unroll
  for (int n=0;n<4;++n) oacc[n] = fz;
  #pragma unroll
  for (int p=0;p<4;++p){ mrun[p] = -1e30f; lrun[p] = 0.f; }

  const int lstart0 = (T_-64) - i0;
  for (int tI=ts; tI<te; ++tI){
    const int j0 = tI*64;
    const int lstart = lstart0 + j0;
    bf16x8 kf[4][2];
    #pragma unroll
    for (int n=0;n<4;++n){
      const unsigned short* kp = kb + ((size_t)bh*T_ + j0 + 16*n + q15)*64 + 8*g;
      kf[n][0] = *(const bf16x8*)kp;
      kf[n][1] = *(const bf16x8*)(kp+32);
    }
    const int key = tid & 63, sh = tid >> 6;
    bf16x8 vv0 = *(const bf16x8*)(vb + ((size_t)bh*T_ + j0 + key)*64 + 8*sh);
    bf16x8 vv1 = *(const bf16x8*)(vb + ((size_t)bh*T_ + j0 + key)*64 + 8*sh + 32);
    __syncthreads();
    #pragma unroll
    for (int jj=0;jj<8;++jj) Vt[8*sh+jj][key]    = (unsigned short)vv0[jj];
    #pragma unroll
    for (int jj=0;jj<8;++jj) Vt[8*sh+32+jj][key] = (unsigned short)vv1[jj];

    // QE rolling window: first processed tile fills 128 slots, later tiles 64
    const int nhalf = (tI==ts) ? 2 : 1;
    for (int hf=0; hf<nhalf; ++hf){
      const int lb = (tI==ts) ? (lstart + 64*hf) : (lstart + 64);
      bf16x8 pe[4][4];
      #pragma unroll
      for (int g2=0; g2<4; ++g2){
        int ln = lb + 16*g2 + q15;
        int l = (ln > T_-1) ? (T_-1) : ln;
        const unsigned short* ep  = eh + ((size_t)h*T_ + l)*64 + 8*g;
        const unsigned short* ep2 = el + ((size_t)h*T_ + l)*64 + 8*g;
        pe[g2][0] = *(const bf16x8*)ep;
        pe[g2][1] = *(const bf16x8*)(ep+32);
        pe[g2][2] = *(const bf16x8*)ep2;
        pe[g2][3] = *(const bf16x8*)(ep2+32);
      }
      #pragma unroll
      for (int g2=0; g2<4; ++g2){
        int slot = (lb + 16*g2 + q15) & 127;
        f32x4 qe = {0.f,0.f,0.f,0.f};
        qe = MFMA(qa00, pe[g2][0], qe); qe = MFMA(qa01, pe[g2][1], qe);
        qe = MFMA(qa10, pe[g2][0], qe); qe = MFMA(qa11, pe[g2][1], qe);
        qe = MFMA(qa00, pe[g2][2], qe); qe = MFMA(qa01, pe[g2][3], qe);
        *(f32x4*)&QEs[w][slot][4*g] = qe;
      }
    }
    f32x4 sacc[4];
    #pragma unroll
    for (int n=0;n<4;++n){
      f32x4 s = fz;
      s = MFMA(qa00, kf[n][0], s); s = MFMA(qa01, kf[n][1], s);
      sacc[n] = s;
    }
    const bool lastT = (j0 == i0);           // diagonal tile
    float pv[4][4];
    float tmax[4] = {-1e30f,-1e30f,-1e30f,-1e30f};
    #pragma unroll
    for (int n=0;n<4;++n){
      #pragma unroll
      for (int p=0;p<4;++p){
        int r = 16*w + 4*g + p;
        int c = 16*n + q15;
        int slot = (lstart + 63 - r + c) & 127;
        float s = sacc[n][p] + QEs[w][slot][4*g + p];
        if (lastT && c > r) s = -1e30f;
        pv[n][p] = s;
        tmax[p] = fmaxf(tmax[p], s);
      }
    }
    #pragma unroll
    for (int p=0;p<4;++p){
      float m = tmax[p];
      m = fmaxf(m, __shfl_xor(m,1)); m = fmaxf(m, __shfl_xor(m,2));
      m = fmaxf(m, __shfl_xor(m,4)); m = fmaxf(m, __shfl_xor(m,8));
      float mn = fmaxf(mrun[p], m);
      float al = __expf(mrun[p] - mn);
      mrun[p] = mn;
      lrun[p] *= al;
      oacc[0][p]*=al; oacc[1][p]*=al; oacc[2][p]*=al; oacc[3][p]*=al;
      float sum = 0.f;
      #pragma unroll
      for (int n=0;n<4;++n){
        float e = __expf(pv[n][p] - mn);
        pv[n][p] = e;
        sum += e;
      }
      sum += __shfl_xor(sum,1); sum += __shfl_xor(sum,2);
      sum += __shfl_xor(sum,4); sum += __shfl_xor(sum,8);
      lrun[p] += sum;
      #pragma unroll
      for (int n=0;n<4;++n) Ps[w][4*g+p][16*n+q15] = f2bf(pv[n][p]);
    }
    __syncthreads();
    bf16x8 pa0 = *(const bf16x8*)&Ps[w][q15][8*g];
    bf16x8 pa1 = *(const bf16x8*)&Ps[w][q15][8*g+32];
    #pragma unroll
    for (int ns=0; ns<4; ++ns){
      bf16x8 v0 = *(const bf16x8*)&Vt[16*ns+q15][8*g];
      bf16x8 v1 = *(const bf16x8*)&Vt[16*ns+q15][8*g+32];
      oacc[ns] = MFMA(pa0, v0, oacc[ns]);
      oacc[ns] = MFMA(pa1, v1, oacc[ns]);
    }
  }
  // write partials: per row r, 64 cols + m + l (stride 68 floats)
  #pragma unroll
  for (int p=0;p<4;++p){
    int r = i0 + 16*w + 4*g + p;
    float* prow = part + (((size_t)half*16 + bh)*T_ + r)*68;
    #pragma unroll
    for (int n=0;n<4;++n) prow[16*n + q15] = oacc[n][p];
    if (q15 == 0){ prow[64] = mrun[p]; prow[65] = lrun[p]; }
  }
}

// ---------------- merge partials + masked-row mean(v) + no-transpose scatter -------
__global__ __launch_bounds__(256) void merge_k(
  const float* __restrict__ part, const int* __restrict__ mask,
  const float* __restrict__ vsum, unsigned short* __restrict__ ao)
{
  int idx = blockIdx.x*256 + threadIdx.x;    // [0, 16*2048*64)
  int c  = idx & 63;
  int r  = (idx >> 6) & 2047;
  int bh = idx >> 17;
  int b = bh >> 3, h = bh & 7;
  const float* p0 = part + (((size_t)bh)*T_ + r)*68;
  float m0 = p0[64], l0 = p0[65], o0 = p0[c];
  float val;
  if (r >= 1024){
    const float* p1 = part + (((size_t)(16 + bh))*T_ + r)*68;
    float m1 = p1[64], l1 = p1[65], o1 = p1[c];
    float M = fmaxf(m0, m1);
    float a0 = __expf(m0 - M), a1 = __expf(m1 - M);
    val = (o0*a0 + o1*a1) / (l0*a0 + l1*a1);
  } else {
    val = o0 / l0;
  }
  if (mask[b*T_ + r] == 0) val = vsum[bh*64 + c] * (1.f/2048.f);
  int rr = h*256 + (r >> 3);
  int cc = (r & 7)*64 + c;
  ao[((size_t)(b*T_ + rr))*E_ + cc] = f2bf(val);
}

// ---------------- output projection: out = ao @ Wo^T + bo (bf16 MFMA) ----
__global__ __launch_bounds__(256) void outproj(
  const unsigned short* __restrict__ ao, const unsigned short* __restrict__ wob,
  const float* __restrict__ bo, float* __restrict__ out)
{
  int tid = threadIdx.x;
  int w = tid>>6, lane = tid&63, g = lane>>4, q15 = lane&15;
  int nb = blockIdx.x & 7, rb = blockIdx.x >> 3;
  size_t row = (size_t)rb*64 + 16*w + q15;
  const unsigned short* ap = ao + row*E_ + 8*g;
  const f32x4 fz = {0.f,0.f,0.f,0.f};
  f32x4 acc[4];
  #pragma unroll
  for (int n=0;n<4;++n) acc[n] = fz;
  #pragma unroll 4
  for (int kk=0; kk<16; ++kk){
    bf16x8 a = *(const bf16x8*)(ap + 32*kk);
    #pragma unroll
    for (int n=0;n<4;++n){
      bf16x8 bfr = *(const bf16x8*)(wob + ((size_t)(nb*64 + 16*n + q15))*E_ + 32*kk + 8*g);
      acc[n] = MFMA(a, bfr, acc[n]);
    }
  }
  #pragma unroll
  for (int n=0;n<4;++n){
    int col = nb*64 + 16*n + q15;
    float bv = bo[col];
    #pragma unroll
    for (int p=0;p<4;++p){
      size_t rr = (size_t)rb*64 + 16*w + 4*g + p;
      out[rr*E_ + col] = acc[n][p] + bv;
    }
  }
}

// ---------------- launch -----------------------------------------------------------
extern "C" void kernel_launch(void* const* d_in, const int* in_sizes, int n_in,
                              void* d_out, int out_size, void* d_ws, size_t ws_size,
                              hipStream_t stream)
{
  int ix=-1, ier=-1, iwo=-1, ibo=-1, c4[4], nc=0;
  for (int i=0;i<n_in;++i){
    switch(in_sizes[i]){
      case 2097152: ix  = i; break;
      case 1048576: ier = i; break;
      case 262144:  iwo = i; break;
      case 512:     ibo = i; break;
      case 4096:    if (nc<4) c4[nc++] = i; break;
      default: break;
    }
  }
  if (ix<0||ier<0||iwo<0||ibo<0||nc!=4){ ix=0;c4[0]=1;c4[1]=3;c4[2]=4;c4[3]=5;ier=6;iwo=7;ibo=8; }
  const float* x  = (const float*)d_in[ix];
  const int* mask = (const int*)d_in[c4[0]];
  const float* Wq = (const float*)d_in[c4[1]];
  const float* Wk = (const float*)d_in[c4[2]];
  const float* Wv = (const float*)d_in[c4[3]];
  const float* Er = (const float*)d_in[ier];
  const float* Wo = (const float*)d_in[iwo];
  const float* bo = (const float*)d_in[ibo];
  float* out = (float*)d_out;

  char* ws = (char*)d_ws;
  unsigned short* qh  = (unsigned short*)(ws + 0);
  unsigned short* ql  = (unsigned short*)(ws + 4194304);
  unsigned short* kb  = (unsigned short*)(ws + 8388608);
  unsigned short* vb  = (unsigned short*)(ws + 12582912);
  unsigned short* eh  = (unsigned short*)(ws + 16777216);
  unsigned short* el  = (unsigned short*)(ws + 18874368);
  unsigned short* wob = (unsigned short*)(ws + 20971520);
  unsigned short* ao  = (unsigned short*)(ws + 21495808);
  float* vsum  = (float*)(ws + 25690112);
  float* vpart = (float*)(ws + 25694208);
  float* part  = (float*)(ws + 25790464);   // 2*16*2048*68*4B = 17.8MB -> ends ~43.6MB

  hipLaunchKernelGGL(prep_qkv, dim3(3072), dim3(256), 0, stream, x, Wq, Wk, Wv, qh, ql, kb, vb);
  hipLaunchKernelGGL(prep_er,  dim3(1024), dim3(256), 0, stream, Er, eh, el);
  hipLaunchKernelGGL(prep_wo,  dim3(256),  dim3(256), 0, stream, Wo, wob);
  hipLaunchKernelGGL(vsum1,    dim3(128),  dim3(256), 0, stream, vb, vpart);
  hipLaunchKernelGGL(vsum2,    dim3(16),   dim3(64),  0, stream, vpart, vsum);
  hipLaunchKernelGGL(attn,     dim3(768),  dim3(256), 0, stream, qh, ql, kb, vb, eh, el, part);
  hipLaunchKernelGGL(merge_k,  dim3(8192), dim3(256), 0, stream, part, mask, vsum, ao);
  hipLaunchKernelGGL(outproj,  dim3(512),  dim3(256), 0, stream, ao, wob, bo, out);
}

// Round 23
// 256.364 us; speedup vs baseline: 1.0604x; 1.0604x over previous
//
#include <hip/hip_runtime.h>

// Round 23 — split-K (768 blocks, <=16 steps) + LDS diet 59392->53248B so all
// blocks are CO-RESIDENT at 3 blocks/CU (this is what R21/R22 each lacked):
//   QEs stride 20->17 floats (coprime w/ 32 banks), launch_bounds(256,3).
// R20-style chained QE MFMA, no setprio (R21's bundle regressed).

#define B_ 2
#define T_ 2048
#define E_ 512
#define H_ 8
#define SCALE2 0.044194173824159216f   // 512^-0.5 folded into k

typedef __attribute__((ext_vector_type(8))) short bf16x8;
typedef __attribute__((ext_vector_type(4))) float f32x4;

#define MFMA(a,b,c) __builtin_amdgcn_mfma_f32_16x16x32_bf16((a),(b),(c),0,0,0)

__device__ __forceinline__ unsigned short f2bf(float f){
  unsigned u = __builtin_bit_cast(unsigned, f);
  u += 0x7fffu + ((u >> 16) & 1u);
  return (unsigned short)(u >> 16);
}
__device__ __forceinline__ float bf2f(unsigned short h){
  unsigned u = ((unsigned)h) << 16;
  return __builtin_bit_cast(float, u);
}

// ---------------- QKV projection ----
__global__ __launch_bounds__(256) void prep_qkv(
    const float* __restrict__ x,
    const float* __restrict__ Wq, const float* __restrict__ Wk, const float* __restrict__ Wv,
    unsigned short* __restrict__ qh, unsigned short* __restrict__ ql,
    unsigned short* __restrict__ kb, unsigned short* __restrict__ vb)
{
  int wid = blockIdx.x*4 + (threadIdx.x>>6);
  int o   = threadIdx.x & 63;
  int bh  = wid & 15;
  int rest = wid >> 4;
  int chunk = rest & 255;
  int m = rest >> 8;
  const float* W = (m==0) ? Wq : (m==1) ? Wk : Wv;
  float4 wv[16];
  #pragma unroll
  for (int j=0;j<16;++j) wv[j] = reinterpret_cast<const float4*>(W)[o*16+j];
  if (m==1){
    #pragma unroll
    for (int j=0;j<16;++j){ wv[j].x*=SCALE2; wv[j].y*=SCALE2; wv[j].z*=SCALE2; wv[j].w*=SCALE2; }
  }
  int b = bh>>3, h = bh&7;
  unsigned short* out0 = (m==0) ? qh : (m==1) ? kb : vb;
  for (int tl=0; tl<8; ++tl){
    int t = chunk*8 + tl;
    const float4* xr = reinterpret_cast<const float4*>(x + ((size_t)(b*T_ + t))*E_ + h*64);
    float a0=0.f,a1=0.f,a2=0.f,a3=0.f;
    #pragma unroll
    for (int j=0;j<16;++j){
      float4 xv = xr[j];
      a0 += xv.x*wv[j].x; a1 += xv.y*wv[j].y; a2 += xv.z*wv[j].z; a3 += xv.w*wv[j].w;
    }
    float acc = (a0+a1)+(a2+a3);
    size_t oi = ((size_t)bh*T_ + t)*64 + o;
    if (m==0){
      unsigned short hq = f2bf(acc);
      out0[oi] = hq;
      ql[oi] = f2bf(acc - bf2f(hq));
    } else {
      out0[oi] = f2bf(acc);
    }
  }
}

__global__ void prep_er(const float* __restrict__ Er,
                        unsigned short* __restrict__ eh, unsigned short* __restrict__ el)
{
  int i = (blockIdx.x*blockDim.x + threadIdx.x)*4;
  float4 v = *reinterpret_cast<const float4*>(Er + i);
  unsigned short h0=f2bf(v.x), h1=f2bf(v.y), h2=f2bf(v.z), h3=f2bf(v.w);
  *reinterpret_cast<ushort4*>(&eh[i]) = make_ushort4(h0,h1,h2,h3);
  *reinterpret_cast<ushort4*>(&el[i]) = make_ushort4(
      f2bf(v.x-bf2f(h0)), f2bf(v.y-bf2f(h1)), f2bf(v.z-bf2f(h2)), f2bf(v.w-bf2f(h3)));
}

__global__ void prep_wo(const float* __restrict__ Wo, unsigned short* __restrict__ wob){
  int i = (blockIdx.x*blockDim.x + threadIdx.x)*4;
  float4 v = *reinterpret_cast<const float4*>(Wo + i);
  *reinterpret_cast<ushort4*>(&wob[i]) = make_ushort4(f2bf(v.x),f2bf(v.y),f2bf(v.z),f2bf(v.w));
}

__global__ __launch_bounds__(256) void vsum1(const unsigned short* __restrict__ vb,
                                             float* __restrict__ vpart)
{
  __shared__ float red[4][64];
  int bh = blockIdx.x >> 3, ch = blockIdx.x & 7;
  int s = threadIdx.x & 63, sub = threadIdx.x >> 6;
  const unsigned short* p = vb + ((size_t)bh*T_ + ch*256 + sub*64)*64 + s;
  float acc = 0.f;
  #pragma unroll 8
  for (int t=0;t<64;++t) acc += bf2f(p[(size_t)t*64]);
  red[sub][s] = acc;
  __syncthreads();
  if (sub==0) vpart[(size_t)(bh*8+ch)*64 + s] = red[0][s]+red[1][s]+red[2][s]+red[3][s];
}
__global__ void vsum2(const float* __restrict__ vpart, float* __restrict__ vsum){
  int bh = blockIdx.x, s = threadIdx.x;
  float a = 0.f;
  #pragma unroll
  for (int c=0;c<8;++c) a += vpart[(size_t)(bh*8+c)*64 + s];
  vsum[bh*64+s] = a;
}

// ---------------- split-K flash attention: writes partials (o[64], m, l) ----------
__global__ __launch_bounds__(256,3) void attn(
  const unsigned short* __restrict__ qh, const unsigned short* __restrict__ ql,
  const unsigned short* __restrict__ kb, const unsigned short* __restrict__ vb,
  const unsigned short* __restrict__ eh, const unsigned short* __restrict__ el,
  float* __restrict__ part)
{
  __shared__ float QEs[4][128][17];          // 34816B; stride 17 coprime w/ banks
  __shared__ unsigned short Ps[4][16][72];   // 9216B
  __shared__ unsigned short Vt[64][72];      // 9216B  -> 53248B => 3 blocks/CU

  const int tid = threadIdx.x;
  const int w = tid >> 6, lane = tid & 63, g = lane >> 4, q15 = lane & 15;
  const int bid = blockIdx.x;
  const int bh = bid & 15;
  const int unit = bid >> 4;                 // 0..47
  int rt, ts, te, half;
  if (unit < 16){ rt = unit; ts = 0; te = rt+1; half = 0; }
  else {
    int j = unit - 16;
    rt = 16 + (j >> 1);
    half = j & 1;
    int nt = rt + 1;
    int nh = (nt + 1) >> 1;
    if (half == 0){ ts = 0; te = nh; } else { ts = nh; te = nt; }
  }
  const int i0 = rt * 64;
  const int h = bh & 7;

  const size_t qoff = ((size_t)bh*T_ + i0 + 16*w + q15)*64 + 8*g;
  const bf16x8 qa00 = *(const bf16x8*)(qh + qoff);
  const bf16x8 qa01 = *(const bf16x8*)(qh + qoff + 32);
  const bf16x8 qa10 = *(const bf16x8*)(ql + qoff);
  const bf16x8 qa11 = *(const bf16x8*)(ql + qoff + 32);

  f32x4 oacc[4];
  float mrun[4], lrun[4];
  const f32x4 fz = {0.f,0.f,0.f,0.f};
  #pragma unroll
  for (int n=0;n<4;++n) oacc[n] = fz;
  #pragma unroll
  for (int p=0;p<4;++p){ mrun[p] = -1e30f; lrun[p] = 0.f; }

  const int lstart0 = (T_-64) - i0;
  for (int tI=ts; tI<te; ++tI){
    const int j0 = tI*64;
    const int lstart = lstart0 + j0;
    bf16x8 kf[4][2];
    #pragma unroll
    for (int n=0;n<4;++n){
      const unsigned short* kp = kb + ((size_t)bh*T_ + j0 + 16*n + q15)*64 + 8*g;
      kf[n][0] = *(const bf16x8*)kp;
      kf[n][1] = *(const bf16x8*)(kp+32);
    }
    const int key = tid & 63, sh = tid >> 6;
    bf16x8 vv0 = *(const bf16x8*)(vb + ((size_t)bh*T_ + j0 + key)*64 + 8*sh);
    bf16x8 vv1 = *(const bf16x8*)(vb + ((size_t)bh*T_ + j0 + key)*64 + 8*sh + 32);
    __syncthreads();
    #pragma unroll
    for (int jj=0;jj<8;++jj) Vt[8*sh+jj][key]    = (unsigned short)vv0[jj];
    #pragma unroll
    for (int jj=0;jj<8;++jj) Vt[8*sh+32+jj][key] = (unsigned short)vv1[jj];

    // QE rolling window: first processed tile fills 128 slots, later tiles 64
    const int nhalf = (tI==ts) ? 2 : 1;
    for (int hf=0; hf<nhalf; ++hf){
      const int lb = (tI==ts) ? (lstart + 64*hf) : (lstart + 64);
      bf16x8 pe[4][4];
      #pragma unroll
      for (int g2=0; g2<4; ++g2){
        int ln = lb + 16*g2 + q15;
        int l = (ln > T_-1) ? (T_-1) : ln;
        const unsigned short* ep  = eh + ((size_t)h*T_ + l)*64 + 8*g;
        const unsigned short* ep2 = el + ((size_t)h*T_ + l)*64 + 8*g;
        pe[g2][0] = *(const bf16x8*)ep;
        pe[g2][1] = *(const bf16x8*)(ep+32);
        pe[g2][2] = *(const bf16x8*)ep2;
        pe[g2][3] = *(const bf16x8*)(ep2+32);
      }
      #pragma unroll
      for (int g2=0; g2<4; ++g2){
        int slot = (lb + 16*g2 + q15) & 127;
        f32x4 qe = {0.f,0.f,0.f,0.f};
        qe = MFMA(qa00, pe[g2][0], qe); qe = MFMA(qa01, pe[g2][1], qe);
        qe = MFMA(qa10, pe[g2][0], qe); qe = MFMA(qa11, pe[g2][1], qe);
        qe = MFMA(qa00, pe[g2][2], qe); qe = MFMA(qa01, pe[g2][3], qe);
        #pragma unroll
        for (int jq=0;jq<4;++jq) QEs[w][slot][4*g+jq] = qe[jq];
      }
    }
    f32x4 sacc[4];
    #pragma unroll
    for (int n=0;n<4;++n){
      f32x4 s = fz;
      s = MFMA(qa00, kf[n][0], s); s = MFMA(qa01, kf[n][1], s);
      sacc[n] = s;
    }
    const bool lastT = (j0 == i0);           // diagonal tile
    float pv[4][4];
    float tmax[4] = {-1e30f,-1e30f,-1e30f,-1e30f};
    #pragma unroll
    for (int n=0;n<4;++n){
      #pragma unroll
      for (int p=0;p<4;++p){
        int r = 16*w + 4*g + p;
        int c = 16*n + q15;
        int slot = (lstart + 63 - r + c) & 127;
        float s = sacc[n][p] + QEs[w][slot][4*g + p];
        if (lastT && c > r) s = -1e30f;
        pv[n][p] = s;
        tmax[p] = fmaxf(tmax[p], s);
      }
    }
    #pragma unroll
    for (int p=0;p<4;++p){
      float m = tmax[p];
      m = fmaxf(m, __shfl_xor(m,1)); m = fmaxf(m, __shfl_xor(m,2));
      m = fmaxf(m, __shfl_xor(m,4)); m = fmaxf(m, __shfl_xor(m,8));
      float mn = fmaxf(mrun[p], m);
      float al = __expf(mrun[p] - mn);
      mrun[p] = mn;
      lrun[p] *= al;
      oacc[0][p]*=al; oacc[1][p]*=al; oacc[2][p]*=al; oacc[3][p]*=al;
      float sum = 0.f;
      #pragma unroll
      for (int n=0;n<4;++n){
        float e = __expf(pv[n][p] - mn);
        pv[n][p] = e;
        sum += e;
      }
      sum += __shfl_xor(sum,1); sum += __shfl_xor(sum,2);
      sum += __shfl_xor(sum,4); sum += __shfl_xor(sum,8);
      lrun[p] += sum;
      #pragma unroll
      for (int n=0;n<4;++n) Ps[w][4*g+p][16*n+q15] = f2bf(pv[n][p]);
    }
    __syncthreads();
    bf16x8 pa0 = *(const bf16x8*)&Ps[w][q15][8*g];
    bf16x8 pa1 = *(const bf16x8*)&Ps[w][q15][8*g+32];
    #pragma unroll
    for (int ns=0; ns<4; ++ns){
      bf16x8 v0 = *(const bf16x8*)&Vt[16*ns+q15][8*g];
      bf16x8 v1 = *(const bf16x8*)&Vt[16*ns+q15][8*g+32];
      oacc[ns] = MFMA(pa0, v0, oacc[ns]);
      oacc[ns] = MFMA(pa1, v1, oacc[ns]);
    }
  }
  // write partials: per row r, 64 cols + m + l (stride 68 floats)
  #pragma unroll
  for (int p=0;p<4;++p){
    int r = i0 + 16*w + 4*g + p;
    float* prow = part + (((size_t)half*16 + bh)*T_ + r)*68;
    #pragma unroll
    for (int n=0;n<4;++n) prow[16*n + q15] = oacc[n][p];
    if (q15 == 0){ prow[64] = mrun[p]; prow[65] = lrun[p]; }
  }
}

// ---------------- merge partials + masked-row mean(v) + no-transpose scatter -------
__global__ __launch_bounds__(256) void merge_k(
  const float* __restrict__ part, const int* __restrict__ mask,
  const float* __restrict__ vsum, unsigned short* __restrict__ ao)
{
  int idx = blockIdx.x*256 + threadIdx.x;    // [0, 16*2048*64)
  int c  = idx & 63;
  int r  = (idx >> 6) & 2047;
  int bh = idx >> 17;
  int b = bh >> 3, h = bh & 7;
  const float* p0 = part + (((size_t)bh)*T_ + r)*68;
  float m0 = p0[64], l0 = p0[65], o0 = p0[c];
  float val;
  if (r >= 1024){
    const float* p1 = part + (((size_t)(16 + bh))*T_ + r)*68;
    float m1 = p1[64], l1 = p1[65], o1 = p1[c];
    float M = fmaxf(m0, m1);
    float a0 = __expf(m0 - M), a1 = __expf(m1 - M);
    val = (o0*a0 + o1*a1) / (l0*a0 + l1*a1);
  } else {
    val = o0 / l0;
  }
  if (mask[b*T_ + r] == 0) val = vsum[bh*64 + c] * (1.f/2048.f);
  int rr = h*256 + (r >> 3);
  int cc = (r & 7)*64 + c;
  ao[((size_t)(b*T_ + rr))*E_ + cc] = f2bf(val);
}

// ---------------- output projection: out = ao @ Wo^T + bo (bf16 MFMA) ----
__global__ __launch_bounds__(256) void outproj(
  const unsigned short* __restrict__ ao, const unsigned short* __restrict__ wob,
  const float* __restrict__ bo, float* __restrict__ out)
{
  int tid = threadIdx.x;
  int w = tid>>6, lane = tid&63, g = lane>>4, q15 = lane&15;
  int nb = blockIdx.x & 7, rb = blockIdx.x >> 3;
  size_t row = (size_t)rb*64 + 16*w + q15;
  const unsigned short* ap = ao + row*E_ + 8*g;
  const f32x4 fz = {0.f,0.f,0.f,0.f};
  f32x4 acc[4];
  #pragma unroll
  for (int n=0;n<4;++n) acc[n] = fz;
  #pragma unroll 4
  for (int kk=0; kk<16; ++kk){
    bf16x8 a = *(const bf16x8*)(ap + 32*kk);
    #pragma unroll
    for (int n=0;n<4;++n){
      bf16x8 bfr = *(const bf16x8*)(wob + ((size_t)(nb*64 + 16*n + q15))*E_ + 32*kk + 8*g);
      acc[n] = MFMA(a, bfr, acc[n]);
    }
  }
  #pragma unroll
  for (int n=0;n<4;++n){
    int col = nb*64 + 16*n + q15;
    float bv = bo[col];
    #pragma unroll
    for (int p=0;p<4;++p){
      size_t rr = (size_t)rb*64 + 16*w + 4*g + p;
      out[rr*E_ + col] = acc[n][p] + bv;
    }
  }
}

// ---------------- launch -----------------------------------------------------------
extern "C" void kernel_launch(void* const* d_in, const int* in_sizes, int n_in,
                              void* d_out, int out_size, void* d_ws, size_t ws_size,
                              hipStream_t stream)
{
  int ix=-1, ier=-1, iwo=-1, ibo=-1, c4[4], nc=0;
  for (int i=0;i<n_in;++i){
    switch(in_sizes[i]){
      case 2097152: ix  = i; break;
      case 1048576: ier = i; break;
      case 262144:  iwo = i; break;
      case 512:     ibo = i; break;
      case 4096:    if (nc<4) c4[nc++] = i; break;
      default: break;
    }
  }
  if (ix<0||ier<0||iwo<0||ibo<0||nc!=4){ ix=0;c4[0]=1;c4[1]=3;c4[2]=4;c4[3]=5;ier=6;iwo=7;ibo=8; }
  const float* x  = (const float*)d_in[ix];
  const int* mask = (const int*)d_in[c4[0]];
  const float* Wq = (const float*)d_in[c4[1]];
  const float* Wk = (const float*)d_in[c4[2]];
  const float* Wv = (const float*)d_in[c4[3]];
  const float* Er = (const float*)d_in[ier];
  const float* Wo = (const float*)d_in[iwo];
  const float* bo = (const float*)d_in[ibo];
  float* out = (float*)d_out;

  char* ws = (char*)d_ws;
  unsigned short* qh  = (unsigned short*)(ws + 0);
  unsigned short* ql  = (unsigned short*)(ws + 4194304);
  unsigned short* kb  = (unsigned short*)(ws + 8388608);
  unsigned short* vb  = (unsigned short*)(ws + 12582912);
  unsigned short* eh  = (unsigned short*)(ws + 16777216);
  unsigned short* el  = (unsigned short*)(ws + 18874368);
  unsigned short* wob = (unsigned short*)(ws + 20971520);
  unsigned short* ao  = (unsigned short*)(ws + 21495808);
  float* vsum  = (float*)(ws + 25690112);
  float* vpart = (float*)(ws + 25694208);
  float* part  = (float*)(ws + 25790464);   // 2*16*2048*68*4B = 17.8MB

  hipLaunchKernelGGL(prep_qkv, dim3(3072), dim3(256), 0, stream, x, Wq, Wk, Wv, qh, ql, kb, vb);
  hipLaunchKernelGGL(prep_er,  dim3(1024), dim3(256), 0, stream, Er, eh, el);
  hipLaunchKernelGGL(prep_wo,  dim3(256),  dim3(256), 0, stream, Wo, wob);
  hipLaunchKernelGGL(vsum1,    dim3(128),  dim3(256), 0, stream, vb, vpart);
  hipLaunchKernelGGL(vsum2,    dim3(16),   dim3(64),  0, stream, vpart, vsum);
  hipLaunchKernelGGL(attn,     dim3(768),  dim3(256), 0, stream, qh, ql, kb, vb, eh, el, part);
  hipLaunchKernelGGL(merge_k,  dim3(8192), dim3(256), 0, stream, part, mask, vsum, ao);
  hipLaunchKernelGGL(outproj,  dim3(512),  dim3(256), 0, stream, ao, wob, bo, out);
}